// Round 10
// baseline (428.497 us; speedup 1.0000x reference)
//
#include <hip/hip_runtime.h>
#include <hip/hip_bf16.h>

#define CH 8
#define SEC 32768
#define FIN 64
#define FOUT 64
#define UN 512
#define BM 128

typedef __bf16 bf16;
typedef bf16 bf16x8 __attribute__((ext_vector_type(8)));
typedef bf16 bf16x4 __attribute__((ext_vector_type(4)));
typedef float f32x4 __attribute__((ext_vector_type(4)));

// load 8 consecutive fp32 and convert to bf16x8
__device__ __forceinline__ bf16x8 cvt8(const float* __restrict__ src) {
  f32x4 u0 = *(const f32x4*)src;
  f32x4 u1 = *(const f32x4*)(src + 4);
  bf16x8 v;
  v[0] = (bf16)u0[0]; v[1] = (bf16)u0[1]; v[2] = (bf16)u0[2]; v[3] = (bf16)u0[3];
  v[4] = (bf16)u1[0]; v[5] = (bf16)u1[1]; v[6] = (bf16)u1[2]; v[7] = (bf16)u1[3];
  return v;
}

__device__ __forceinline__ void store_cvt8(void* dst, const float* __restrict__ src) {
  *(bf16x8*)dst = cvt8(src);
}

// ---------------------------------------------------------------------------
// Main layer, BM=128, 16 waves, SWAPPED MFMA operands (acc = mfma(W, X)).
// act layout: [8 gmt][NKS][64 lanes][16B] (128 KiB at K=512).
// Wave tile 64x64: wm = w>>3 -> rows, wn = w&7 -> cols.
// B: REGISTER DOUBLE-BUFFER global->reg from swizzled d_ws, static j+=2
// alternation (B0/B1) -> panel j+1's loads fly under panel j's MFMAs.
// All offsets compile-time immediates (no rot) -> addr regs stay small,
// ~85 VGPR + 64 AGPR fits 4 waves/SIMD without spill.
// Epilogue: lane holds m=l15, n=l4*4+r (4 consecutive features) -> one
// ds_write_b64 per (mt,nt) in next layer's frag order.
// ---------------------------------------------------------------------------
template<int K, bool WSPATH>
__device__ __forceinline__ void run_main_layer(
    const bf16* __restrict__ wb,   // swizzled layout when WSPATH
    const float* __restrict__ wf,  // raw [N][K] fp32 fallback
    const float* __restrict__ bias, char* __restrict__ act,
    int w, int l, int l15, int l4, int wm, int wn)
{
  constexpr int NKS = K / 32;
  const int col0 = wn * 64;
  const char* abase = act + wm * (4 * NKS * 1024) + l * 16;

  f32x4 acc[4][4];   // [mt][nt]
#pragma unroll
  for (int mt = 0; mt < 4; ++mt)
#pragma unroll
    for (int nt = 0; nt < 4; ++nt)
      acc[mt][nt] = f32x4{0.f, 0.f, 0.f, 0.f};

  if constexpr (WSPATH) {
    const bf16* bp = wb + ((size_t)(wn * 4) * NKS * 64 + l) * 8;
    bf16x8 B0[4], B1[4];
#pragma unroll
    for (int i = 0; i < 4; ++i)
      B0[i] = *(const bf16x8*)(bp + (size_t)(i * NKS) * 512);

#pragma unroll
    for (int j = 0; j < NKS; j += 2) {
      if (j + 1 < NKS) {
#pragma unroll
        for (int i = 0; i < 4; ++i)
          B1[i] = *(const bf16x8*)(bp + (size_t)(i * NKS + j + 1) * 512);
      }
      {
        bf16x8 a[4];
#pragma unroll
        for (int mt = 0; mt < 4; ++mt)
          a[mt] = *(const bf16x8*)(abase + (mt * NKS + j) * 1024);
        __builtin_amdgcn_s_setprio(1);
#pragma unroll
        for (int mt = 0; mt < 4; ++mt)
#pragma unroll
          for (int nt = 0; nt < 4; ++nt)
            acc[mt][nt] = __builtin_amdgcn_mfma_f32_16x16x32_bf16(B0[nt], a[mt], acc[mt][nt], 0, 0, 0);
        __builtin_amdgcn_s_setprio(0);
      }
      if (j + 2 < NKS) {
#pragma unroll
        for (int i = 0; i < 4; ++i)
          B0[i] = *(const bf16x8*)(bp + (size_t)(i * NKS + j + 2) * 512);
      }
      if (j + 1 < NKS) {
        bf16x8 a[4];
#pragma unroll
        for (int mt = 0; mt < 4; ++mt)
          a[mt] = *(const bf16x8*)(abase + (mt * NKS + j + 1) * 1024);
        __builtin_amdgcn_s_setprio(1);
#pragma unroll
        for (int mt = 0; mt < 4; ++mt)
#pragma unroll
          for (int nt = 0; nt < 4; ++nt)
            acc[mt][nt] = __builtin_amdgcn_mfma_f32_16x16x32_bf16(B1[nt], a[mt], acc[mt][nt], 0, 0, 0);
        __builtin_amdgcn_s_setprio(0);
      }
    }
  } else {
    const float* bpf[4];
#pragma unroll
    for (int nt = 0; nt < 4; ++nt)
      bpf[nt] = wf + (size_t)(col0 + nt * 16 + l15) * K + l4 * 8;
#pragma unroll
    for (int j = 0; j < NKS; ++j) {
      bf16x8 a[4], b[4];
#pragma unroll
      for (int nt = 0; nt < 4; ++nt) b[nt] = cvt8(bpf[nt] + j * 32);
#pragma unroll
      for (int mt = 0; mt < 4; ++mt)
        a[mt] = *(const bf16x8*)(abase + (mt * NKS + j) * 1024);
#pragma unroll
      for (int mt = 0; mt < 4; ++mt)
#pragma unroll
        for (int nt = 0; nt < 4; ++nt)
          acc[mt][nt] = __builtin_amdgcn_mfma_f32_16x16x32_bf16(b[nt], a[mt], acc[mt][nt], 0, 0, 0);
    }
  }

  __syncthreads();  // all waves done reading act for this layer

  // epilogue: bias+relu, pack 4 consecutive n per thread -> one ds_write_b64
#pragma unroll
  for (int nt = 0; nt < 4; ++nt) {
    const f32x4 bv = *(const f32x4*)(bias + col0 + nt * 16 + l4 * 4);
    const int slot = l15 + ((nt & 1) * 2 + (l4 >> 1)) * 16;
    const int ksp  = wn * 2 + (nt >> 1);
    const int boff = slot * 16 + (l4 & 1) * 8;
#pragma unroll
    for (int mt = 0; mt < 4; ++mt) {
      bf16x4 pk;
#pragma unroll
      for (int r = 0; r < 4; ++r) {
        const float v = acc[mt][nt][r] + bv[r];
        pk[r] = (bf16)(v > 0.f ? v : 0.f);
      }
      *(bf16x4*)(act + ((wm * 4 + mt) * 16 + ksp) * 1024 + boff) = pk;
    }
  }
  __syncthreads();  // act ready for next layer
}

// ---------------------------------------------------------------------------
// Final layer, BM=128, 16 waves, swapped operands, register dbuf.
// rg = w>>2 -> rows rg*32 (2 mtiles), cg = w&3 -> 16-col frag.
// Lane: m = mt*16+l15, 4 consecutive cols -> ONE global_store_dwordx4.
// ---------------------------------------------------------------------------
template<bool WSPATH>
__device__ __forceinline__ void run_final_layer(
    const bf16* __restrict__ wb, const float* __restrict__ wf,
    const float* __restrict__ bias, const char* __restrict__ act,
    float* __restrict__ gout,
    int w, int l, int l15, int l4)
{
  constexpr int NKS = 16;
  const int rg = w >> 2, cg = w & 3;
  const char* abase = act + (rg * 2) * (NKS * 1024) + l * 16;

  f32x4 acc[2];
  acc[0] = f32x4{0.f, 0.f, 0.f, 0.f};
  acc[1] = f32x4{0.f, 0.f, 0.f, 0.f};

  if constexpr (WSPATH) {
    const bf16* bp = wb + ((size_t)cg * 16 * 64 + l) * 8;
    bf16x8 B0 = *(const bf16x8*)(bp), B1;
#pragma unroll
    for (int j = 0; j < NKS; j += 2) {
      {
        B1 = *(const bf16x8*)(bp + (size_t)(j + 1) * 512);
        const bf16x8 a0 = *(const bf16x8*)(abase + j * 1024);
        const bf16x8 a1 = *(const bf16x8*)(abase + (NKS + j) * 1024);
        acc[0] = __builtin_amdgcn_mfma_f32_16x16x32_bf16(B0, a0, acc[0], 0, 0, 0);
        acc[1] = __builtin_amdgcn_mfma_f32_16x16x32_bf16(B0, a1, acc[1], 0, 0, 0);
      }
      {
        if (j + 2 < NKS) B0 = *(const bf16x8*)(bp + (size_t)(j + 2) * 512);
        const bf16x8 a0 = *(const bf16x8*)(abase + (j + 1) * 1024);
        const bf16x8 a1 = *(const bf16x8*)(abase + (NKS + j + 1) * 1024);
        acc[0] = __builtin_amdgcn_mfma_f32_16x16x32_bf16(B1, a0, acc[0], 0, 0, 0);
        acc[1] = __builtin_amdgcn_mfma_f32_16x16x32_bf16(B1, a1, acc[1], 0, 0, 0);
      }
    }
  } else {
    const float* bpf = wf + (size_t)(cg * 16 + l15) * UN + l4 * 8;
#pragma unroll
    for (int j = 0; j < NKS; ++j) {
      const bf16x8 b  = cvt8(bpf + j * 32);
      const bf16x8 a0 = *(const bf16x8*)(abase + j * 1024);
      const bf16x8 a1 = *(const bf16x8*)(abase + (NKS + j) * 1024);
      acc[0] = __builtin_amdgcn_mfma_f32_16x16x32_bf16(b, a0, acc[0], 0, 0, 0);
      acc[1] = __builtin_amdgcn_mfma_f32_16x16x32_bf16(b, a1, acc[1], 0, 0, 0);
    }
  }

  const f32x4 bv = *(const f32x4*)(bias + cg * 16 + l4 * 4);
#pragma unroll
  for (int i = 0; i < 2; ++i) {
    f32x4 o;
#pragma unroll
    for (int r = 0; r < 4; ++r) o[r] = acc[i][r] + bv[r];
    *(f32x4*)(gout + (size_t)((rg * 2 + i) * 16 + l15) * FOUT + cg * 16 + l4 * 4) = o;
  }
}

template<bool WSPATH>
__global__ __launch_bounds__(1024, 4) void mlp_fused(
    const float* __restrict__ x,
    const float* __restrict__ w0f, const float* __restrict__ w1f,
    const float* __restrict__ w2f, const float* __restrict__ w3f,
    const float* __restrict__ b0, const float* __restrict__ b1,
    const float* __restrict__ b2, const float* __restrict__ b3,
    const bf16* __restrict__ wbase,
    float* __restrict__ out)
{
  extern __shared__ char smem[];
  char* act = smem;  // 128 KiB activations, frag order (only LDS use)

  const int tid = threadIdx.x;
  const int w = tid >> 6, l = tid & 63;
  const int l15 = l & 15, l4 = l >> 4;
  const int wm = w >> 3, wn = w & 7;

  // XCD-chunked swizzle (2048 % 8 == 0 -> bijective): each XCD owns one channel
  const int wg = (blockIdx.x & 7) * 256 + (blockIdx.x >> 3);
  const int ch = wg >> 8;
  const int row0 = (wg & 255) * BM;

  const bf16* w0b = wbase + (size_t)ch * UN * FIN;
  const bf16* w1b = wbase + CH * UN * FIN + (size_t)ch * UN * UN;
  const bf16* w2b = wbase + CH * UN * FIN + CH * UN * UN + (size_t)ch * UN * UN;
  const bf16* w3b = wbase + CH * UN * FIN + 2 * CH * UN * UN + (size_t)ch * FOUT * UN;
  const float* w0c = w0f + (size_t)ch * UN * FIN;
  const float* w1c = w1f + (size_t)ch * UN * UN;
  const float* w2c = w2f + (size_t)ch * UN * UN;
  const float* w3c = w3f + (size_t)ch * FOUT * UN;
  const float* b0c = b0 + ch * UN;
  const float* b1c = b1 + ch * UN;
  const float* b2c = b2 + ch * UN;
  const float* b3c = b3 + ch * FOUT;

  // stage x tile (128 x 64 fp32 -> bf16) into act: slot w = gmt*2 + ks
  {
    const float* xs = x + (size_t)(ch * SEC + row0) * FIN;
    store_cvt8(act + w * 1024 + l * 16,
               xs + ((w >> 1) * 16 + l15) * FIN + (w & 1) * 32 + l4 * 8);
  }
  __syncthreads();

  run_main_layer<64,  WSPATH>(w0b, w0c, b0c, act, w, l, l15, l4, wm, wn);
  run_main_layer<512, WSPATH>(w1b, w1c, b1c, act, w, l, l15, l4, wm, wn);
  run_main_layer<512, WSPATH>(w2b, w2c, b2c, act, w, l, l15, l4, wm, wn);
  run_final_layer<WSPATH>(w3b, w3c, b3c, act,
                          out + (size_t)(ch * SEC + row0) * FOUT,
                          w, l, l15, l4);
}

// ---------------------------------------------------------------------------
// fp32 -> bf16 weight conversion into d_ws, SWIZZLED to MFMA-fragment order:
// per channel, element (f, ks, l, j) = W[f*16 + (l&15)][ks*32 + (l>>4)*8 + j]
// stored at ((f*NKS + ks)*64 + l)*8 + j.
// ---------------------------------------------------------------------------
template<int K, int N>
__device__ __forceinline__ void cvt_one(const float* __restrict__ src,
                                        bf16* __restrict__ dst, int t)
{
  constexpr int NKS = K / 32;
  constexpr int perCh = N * K / 8;   // triples per channel (pow2)
  const int ch = t / perCh;
  const int r = t - ch * perCh;
  const int l = r & 63;
  const int p = r >> 6;
  const int ks = p & (NKS - 1);
  const int f = p / NKS;
  const float* s = src + (size_t)ch * N * K + (size_t)(f * 16 + (l & 15)) * K
                 + ks * 32 + (l >> 4) * 8;
  store_cvt8(dst + (size_t)t * 8, s);
}

__global__ void cvt_weights(const float* __restrict__ w0, const float* __restrict__ w1,
                            const float* __restrict__ w2, const float* __restrict__ w3,
                            bf16* __restrict__ o)
{
  constexpr int T0 = CH * UN * FIN / 8;   // 32768 triples
  constexpr int T1 = CH * UN * UN / 8;    // 262144
  constexpr int total = 2 * T0 + 2 * T1;  // 589824
  for (int t = blockIdx.x * blockDim.x + threadIdx.x; t < total;
       t += gridDim.x * blockDim.x) {
    if (t < T0)                cvt_one<FIN, UN>(w0, o, t);
    else if (t < T0 + T1)      cvt_one<UN, UN>(w1, o + CH * UN * FIN, t - T0);
    else if (t < T0 + 2 * T1)  cvt_one<UN, UN>(w2, o + CH * UN * FIN + CH * UN * UN, t - T0 - T1);
    else                       cvt_one<UN, FOUT>(w3, o + CH * UN * FIN + 2 * CH * UN * UN, t - T0 - 2 * T1);
  }
}

extern "C" void kernel_launch(void* const* d_in, const int* in_sizes, int n_in,
                              void* d_out, int out_size, void* d_ws, size_t ws_size,
                              hipStream_t stream)
{
  const float* x  = (const float*)d_in[0];
  const float* w0 = (const float*)d_in[1];
  const float* w1 = (const float*)d_in[2];
  const float* w2 = (const float*)d_in[3];
  const float* w3 = (const float*)d_in[4];
  const float* b0 = (const float*)d_in[5];
  const float* b1 = (const float*)d_in[6];
  const float* b2 = (const float*)d_in[7];
  const float* b3 = (const float*)d_in[8];
  float* out = (float*)d_out;

  const int grid = CH * (SEC / BM);            // 2048 blocks
  const size_t wbytes = (size_t)(2 * CH * UN * FIN + 2 * CH * UN * UN) * 2;  // 9437184

  if (ws_size >= wbytes) {
    bf16* wb = (bf16*)d_ws;
    hipLaunchKernelGGL(cvt_weights, dim3(2304), dim3(256), 0, stream, w0, w1, w2, w3, wb);
    hipFuncSetAttribute(reinterpret_cast<const void*>(mlp_fused<true>),
                        hipFuncAttributeMaxDynamicSharedMemorySize, 131072);
    hipLaunchKernelGGL(mlp_fused<true>, dim3(grid), dim3(1024), 131072, stream,
                       x, w0, w1, w2, w3, b0, b1, b2, b3, wb, out);
  } else {
    hipFuncSetAttribute(reinterpret_cast<const void*>(mlp_fused<false>),
                        hipFuncAttributeMaxDynamicSharedMemorySize, 131072);
    hipLaunchKernelGGL(mlp_fused<false>, dim3(grid), dim3(1024), 131072, stream,
                       x, w0, w1, w2, w3, b0, b1, b2, b3, (const bf16*)nullptr, out);
  }
}

// Round 11
// 299.268 us; speedup vs baseline: 1.4318x; 1.4318x over previous
//
#include <hip/hip_runtime.h>
#include <hip/hip_bf16.h>

#define CH 8
#define SEC 32768
#define FIN 64
#define FOUT 64
#define UN 512
#define BM 128

typedef __bf16 bf16;
typedef bf16 bf16x8 __attribute__((ext_vector_type(8)));
typedef bf16 bf16x4 __attribute__((ext_vector_type(4)));
typedef float f32x4 __attribute__((ext_vector_type(4)));

// load 8 consecutive fp32 and convert to bf16x8
__device__ __forceinline__ bf16x8 cvt8(const float* __restrict__ src) {
  f32x4 u0 = *(const f32x4*)src;
  f32x4 u1 = *(const f32x4*)(src + 4);
  bf16x8 v;
  v[0] = (bf16)u0[0]; v[1] = (bf16)u0[1]; v[2] = (bf16)u0[2]; v[3] = (bf16)u0[3];
  v[4] = (bf16)u1[0]; v[5] = (bf16)u1[1]; v[6] = (bf16)u1[2]; v[7] = (bf16)u1[3];
  return v;
}

__device__ __forceinline__ void store_cvt8(void* dst, const float* __restrict__ src) {
  *(bf16x8*)dst = cvt8(src);
}

// ---------------------------------------------------------------------------
// Main layer, BM=128, 8 WAVES (512 thr), wave tile 64m x 128n, swapped MFMA
// operands (acc = mfma(W, X)). act: [8 gmt][NKS][64 lanes][16B] (128 KiB).
// wm = w>>2 -> row half (gmt = wm*4+mt); wn = w&3 -> cols wn*128 (nt 0..7).
// Rationale vs R9: per-CU LDS A-read traffic halves (8 waves x 4 reads vs
// 16 x 4) while MFMA/K-step stays -> MFMA-dominant (3.2:1); and 512 thr @
// __launch_bounds__(512,2) = 256-reg budget -> acc(128) + B dbuf(64) fits.
// Epilogue: lane holds m=l15, n=l4*4+r -> one ds_write_b64 per (mt,nt):
//   ksp = wn*4 + (nt>>1); slot-lane = l15 + 16*((nt&1)*2 + (l4>>1));
//   byte = (l4&1)*8.
// ---------------------------------------------------------------------------
template<int K, bool WSPATH>
__device__ __forceinline__ void run_main_layer(
    const bf16* __restrict__ wb,   // swizzled layout when WSPATH
    const float* __restrict__ wf,  // raw [N][K] fp32 fallback
    const float* __restrict__ bias, char* __restrict__ act,
    int w, int l, int l15, int l4, int wm, int wn)
{
  constexpr int NKS = K / 32;
  const int col0 = wn * 128;
  const char* abase = act + wm * (4 * NKS * 1024) + l * 16;

  f32x4 acc[4][8];   // [mt][nt] = 128 AGPR
#pragma unroll
  for (int mt = 0; mt < 4; ++mt)
#pragma unroll
    for (int nt = 0; nt < 8; ++nt)
      acc[mt][nt] = f32x4{0.f, 0.f, 0.f, 0.f};

  if constexpr (WSPATH) {
    const bf16* bp = wb + ((size_t)(wn * 8) * NKS * 64 + l) * 8;
    bf16x8 B0[8], B1[8];
#pragma unroll
    for (int i = 0; i < 8; ++i)
      B0[i] = *(const bf16x8*)(bp + (size_t)(i * NKS) * 512);

#pragma unroll
    for (int j = 0; j < NKS; j += 2) {
      if (j + 1 < NKS) {
#pragma unroll
        for (int i = 0; i < 8; ++i)
          B1[i] = *(const bf16x8*)(bp + (size_t)(i * NKS + j + 1) * 512);
      }
      {
        bf16x8 a[4];
#pragma unroll
        for (int mt = 0; mt < 4; ++mt)
          a[mt] = *(const bf16x8*)(abase + (mt * NKS + j) * 1024);
        __builtin_amdgcn_s_setprio(1);
#pragma unroll
        for (int mt = 0; mt < 4; ++mt)
#pragma unroll
          for (int nt = 0; nt < 8; ++nt)
            acc[mt][nt] = __builtin_amdgcn_mfma_f32_16x16x32_bf16(B0[nt], a[mt], acc[mt][nt], 0, 0, 0);
        __builtin_amdgcn_s_setprio(0);
      }
      if (j + 2 < NKS) {
#pragma unroll
        for (int i = 0; i < 8; ++i)
          B0[i] = *(const bf16x8*)(bp + (size_t)(i * NKS + j + 2) * 512);
      }
      if (j + 1 < NKS) {
        bf16x8 a[4];
#pragma unroll
        for (int mt = 0; mt < 4; ++mt)
          a[mt] = *(const bf16x8*)(abase + (mt * NKS + j + 1) * 1024);
        __builtin_amdgcn_s_setprio(1);
#pragma unroll
        for (int mt = 0; mt < 4; ++mt)
#pragma unroll
          for (int nt = 0; nt < 8; ++nt)
            acc[mt][nt] = __builtin_amdgcn_mfma_f32_16x16x32_bf16(B1[nt], a[mt], acc[mt][nt], 0, 0, 0);
        __builtin_amdgcn_s_setprio(0);
      }
    }
  } else {
    const float* bpf[8];
#pragma unroll
    for (int nt = 0; nt < 8; ++nt)
      bpf[nt] = wf + (size_t)(col0 + nt * 16 + l15) * K + l4 * 8;
#pragma unroll
    for (int j = 0; j < NKS; ++j) {
      bf16x8 a[4], b[8];
#pragma unroll
      for (int nt = 0; nt < 8; ++nt) b[nt] = cvt8(bpf[nt] + j * 32);
#pragma unroll
      for (int mt = 0; mt < 4; ++mt)
        a[mt] = *(const bf16x8*)(abase + (mt * NKS + j) * 1024);
#pragma unroll
      for (int mt = 0; mt < 4; ++mt)
#pragma unroll
        for (int nt = 0; nt < 8; ++nt)
          acc[mt][nt] = __builtin_amdgcn_mfma_f32_16x16x32_bf16(b[nt], a[mt], acc[mt][nt], 0, 0, 0);
    }
  }

  __syncthreads();  // all waves done reading act for this layer

  // epilogue: bias+relu, pack 4 consecutive n per thread -> one ds_write_b64
#pragma unroll
  for (int nt = 0; nt < 8; ++nt) {
    const f32x4 bv = *(const f32x4*)(bias + col0 + nt * 16 + l4 * 4);
    const int slot = l15 + ((nt & 1) * 2 + (l4 >> 1)) * 16;
    const int ksp  = wn * 4 + (nt >> 1);
    const int boff = slot * 16 + (l4 & 1) * 8;
#pragma unroll
    for (int mt = 0; mt < 4; ++mt) {
      bf16x4 pk;
#pragma unroll
      for (int r = 0; r < 4; ++r) {
        const float v = acc[mt][nt][r] + bv[r];
        pk[r] = (bf16)(v > 0.f ? v : 0.f);
      }
      *(bf16x4*)(act + ((wm * 4 + mt) * 16 + ksp) * 1024 + boff) = pk;
    }
  }
  __syncthreads();  // act ready for next layer
}

// ---------------------------------------------------------------------------
// Final layer, 8 waves: wave w owns mtile w (16 rows), ALL 64 cols (4 frags).
// Register dbuf. Lane: m = w*16+l15, 4 consecutive cols -> global_store_dwordx4.
// ---------------------------------------------------------------------------
template<bool WSPATH>
__device__ __forceinline__ void run_final_layer(
    const bf16* __restrict__ wb, const float* __restrict__ wf,
    const float* __restrict__ bias, const char* __restrict__ act,
    float* __restrict__ gout,
    int w, int l, int l15, int l4)
{
  constexpr int NKS = 16;
  const char* abase = act + w * (NKS * 1024) + l * 16;

  f32x4 acc[4];
#pragma unroll
  for (int f = 0; f < 4; ++f) acc[f] = f32x4{0.f, 0.f, 0.f, 0.f};

  if constexpr (WSPATH) {
    const bf16* bp = wb + (size_t)l * 8;
    bf16x8 B0[4], B1[4];
#pragma unroll
    for (int f = 0; f < 4; ++f)
      B0[f] = *(const bf16x8*)(bp + (size_t)(f * NKS) * 512);
#pragma unroll
    for (int j = 0; j < NKS; j += 2) {
      {
#pragma unroll
        for (int f = 0; f < 4; ++f)
          B1[f] = *(const bf16x8*)(bp + (size_t)(f * NKS + j + 1) * 512);
        const bf16x8 a = *(const bf16x8*)(abase + j * 1024);
#pragma unroll
        for (int f = 0; f < 4; ++f)
          acc[f] = __builtin_amdgcn_mfma_f32_16x16x32_bf16(B0[f], a, acc[f], 0, 0, 0);
      }
      {
        if (j + 2 < NKS) {
#pragma unroll
          for (int f = 0; f < 4; ++f)
            B0[f] = *(const bf16x8*)(bp + (size_t)(f * NKS + j + 2) * 512);
        }
        const bf16x8 a = *(const bf16x8*)(abase + (j + 1) * 1024);
#pragma unroll
        for (int f = 0; f < 4; ++f)
          acc[f] = __builtin_amdgcn_mfma_f32_16x16x32_bf16(B1[f], a, acc[f], 0, 0, 0);
      }
    }
  } else {
    const float* bpf[4];
#pragma unroll
    for (int f = 0; f < 4; ++f)
      bpf[f] = wf + (size_t)(f * 16 + l15) * UN + l4 * 8;
#pragma unroll
    for (int j = 0; j < NKS; ++j) {
      const bf16x8 a = *(const bf16x8*)(abase + j * 1024);
#pragma unroll
      for (int f = 0; f < 4; ++f) {
        const bf16x8 b = cvt8(bpf[f] + j * 32);
        acc[f] = __builtin_amdgcn_mfma_f32_16x16x32_bf16(b, a, acc[f], 0, 0, 0);
      }
    }
  }

#pragma unroll
  for (int f = 0; f < 4; ++f) {
    const f32x4 bv = *(const f32x4*)(bias + f * 16 + l4 * 4);
    f32x4 o;
#pragma unroll
    for (int r = 0; r < 4; ++r) o[r] = acc[f][r] + bv[r];
    *(f32x4*)(gout + (size_t)(w * 16 + l15) * FOUT + f * 16 + l4 * 4) = o;
  }
}

template<bool WSPATH>
__global__ __launch_bounds__(512, 2) void mlp_fused(
    const float* __restrict__ x,
    const float* __restrict__ w0f, const float* __restrict__ w1f,
    const float* __restrict__ w2f, const float* __restrict__ w3f,
    const float* __restrict__ b0, const float* __restrict__ b1,
    const float* __restrict__ b2, const float* __restrict__ b3,
    const bf16* __restrict__ wbase,
    float* __restrict__ out)
{
  extern __shared__ char smem[];
  char* act = smem;  // 128 KiB activations, frag order (only LDS use)

  const int tid = threadIdx.x;
  const int w = tid >> 6, l = tid & 63;
  const int l15 = l & 15, l4 = l >> 4;
  const int wm = w >> 2, wn = w & 3;

  // XCD-chunked swizzle (2048 % 8 == 0 -> bijective): each XCD owns one channel
  const int wg = (blockIdx.x & 7) * 256 + (blockIdx.x >> 3);
  const int ch = wg >> 8;
  const int row0 = (wg & 255) * BM;

  const bf16* w0b = wbase + (size_t)ch * UN * FIN;
  const bf16* w1b = wbase + CH * UN * FIN + (size_t)ch * UN * UN;
  const bf16* w2b = wbase + CH * UN * FIN + CH * UN * UN + (size_t)ch * UN * UN;
  const bf16* w3b = wbase + CH * UN * FIN + 2 * CH * UN * UN + (size_t)ch * FOUT * UN;
  const float* w0c = w0f + (size_t)ch * UN * FIN;
  const float* w1c = w1f + (size_t)ch * UN * UN;
  const float* w2c = w2f + (size_t)ch * UN * UN;
  const float* w3c = w3f + (size_t)ch * FOUT * UN;
  const float* b0c = b0 + ch * UN;
  const float* b1c = b1 + ch * UN;
  const float* b2c = b2 + ch * UN;
  const float* b3c = b3 + ch * FOUT;

  // stage x tile (128 x 64 fp32 -> bf16): 16 slots, 8 waves -> 2 slots/wave
  {
    const float* xs = x + (size_t)(ch * SEC + row0) * FIN;
#pragma unroll
    for (int i = 0; i < 2; ++i) {
      const int s = w * 2 + i;   // slot = gmt*2 + ks
      store_cvt8(act + s * 1024 + l * 16,
                 xs + ((s >> 1) * 16 + l15) * FIN + (s & 1) * 32 + l4 * 8);
    }
  }
  __syncthreads();

  run_main_layer<64,  WSPATH>(w0b, w0c, b0c, act, w, l, l15, l4, wm, wn);
  run_main_layer<512, WSPATH>(w1b, w1c, b1c, act, w, l, l15, l4, wm, wn);
  run_main_layer<512, WSPATH>(w2b, w2c, b2c, act, w, l, l15, l4, wm, wn);
  run_final_layer<WSPATH>(w3b, w3c, b3c, act,
                          out + (size_t)(ch * SEC + row0) * FOUT,
                          w, l, l15, l4);
}

// ---------------------------------------------------------------------------
// fp32 -> bf16 weight conversion into d_ws, SWIZZLED to MFMA-fragment order:
// per channel, element (f, ks, l, j) = W[f*16 + (l&15)][ks*32 + (l>>4)*8 + j]
// stored at ((f*NKS + ks)*64 + l)*8 + j.
// ---------------------------------------------------------------------------
template<int K, int N>
__device__ __forceinline__ void cvt_one(const float* __restrict__ src,
                                        bf16* __restrict__ dst, int t)
{
  constexpr int NKS = K / 32;
  constexpr int perCh = N * K / 8;   // triples per channel (pow2)
  const int ch = t / perCh;
  const int r = t - ch * perCh;
  const int l = r & 63;
  const int p = r >> 6;
  const int ks = p & (NKS - 1);
  const int f = p / NKS;
  const float* s = src + (size_t)ch * N * K + (size_t)(f * 16 + (l & 15)) * K
                 + ks * 32 + (l >> 4) * 8;
  store_cvt8(dst + (size_t)t * 8, s);
}

__global__ void cvt_weights(const float* __restrict__ w0, const float* __restrict__ w1,
                            const float* __restrict__ w2, const float* __restrict__ w3,
                            bf16* __restrict__ o)
{
  constexpr int T0 = CH * UN * FIN / 8;   // 32768 triples
  constexpr int T1 = CH * UN * UN / 8;    // 262144
  constexpr int total = 2 * T0 + 2 * T1;  // 589824
  for (int t = blockIdx.x * blockDim.x + threadIdx.x; t < total;
       t += gridDim.x * blockDim.x) {
    if (t < T0)                cvt_one<FIN, UN>(w0, o, t);
    else if (t < T0 + T1)      cvt_one<UN, UN>(w1, o + CH * UN * FIN, t - T0);
    else if (t < T0 + 2 * T1)  cvt_one<UN, UN>(w2, o + CH * UN * FIN + CH * UN * UN, t - T0 - T1);
    else                       cvt_one<UN, FOUT>(w3, o + CH * UN * FIN + 2 * CH * UN * UN, t - T0 - 2 * T1);
  }
}

extern "C" void kernel_launch(void* const* d_in, const int* in_sizes, int n_in,
                              void* d_out, int out_size, void* d_ws, size_t ws_size,
                              hipStream_t stream)
{
  const float* x  = (const float*)d_in[0];
  const float* w0 = (const float*)d_in[1];
  const float* w1 = (const float*)d_in[2];
  const float* w2 = (const float*)d_in[3];
  const float* w3 = (const float*)d_in[4];
  const float* b0 = (const float*)d_in[5];
  const float* b1 = (const float*)d_in[6];
  const float* b2 = (const float*)d_in[7];
  const float* b3 = (const float*)d_in[8];
  float* out = (float*)d_out;

  const int grid = CH * (SEC / BM);            // 2048 blocks
  const size_t wbytes = (size_t)(2 * CH * UN * FIN + 2 * CH * UN * UN) * 2;  // 9437184

  if (ws_size >= wbytes) {
    bf16* wb = (bf16*)d_ws;
    hipLaunchKernelGGL(cvt_weights, dim3(2304), dim3(256), 0, stream, w0, w1, w2, w3, wb);
    hipFuncSetAttribute(reinterpret_cast<const void*>(mlp_fused<true>),
                        hipFuncAttributeMaxDynamicSharedMemorySize, 131072);
    hipLaunchKernelGGL(mlp_fused<true>, dim3(grid), dim3(512), 131072, stream,
                       x, w0, w1, w2, w3, b0, b1, b2, b3, wb, out);
  } else {
    hipFuncSetAttribute(reinterpret_cast<const void*>(mlp_fused<false>),
                        hipFuncAttributeMaxDynamicSharedMemorySize, 131072);
    hipLaunchKernelGGL(mlp_fused<false>, dim3(grid), dim3(512), 131072, stream,
                       x, w0, w1, w2, w3, b0, b1, b2, b3, (const bf16*)nullptr, out);
  }
}

// Round 12
// 294.993 us; speedup vs baseline: 1.4526x; 1.0145x over previous
//
#include <hip/hip_runtime.h>
#include <hip/hip_bf16.h>

#define CH 8
#define SEC 32768
#define FIN 64
#define FOUT 64
#define UN 512
#define BM 128

typedef __bf16 bf16;
typedef bf16 bf16x8 __attribute__((ext_vector_type(8)));
typedef bf16 bf16x4 __attribute__((ext_vector_type(4)));
typedef float f32x4 __attribute__((ext_vector_type(4)));

// load 8 consecutive fp32 and convert to bf16x8
__device__ __forceinline__ bf16x8 cvt8(const float* __restrict__ src) {
  f32x4 u0 = *(const f32x4*)src;
  f32x4 u1 = *(const f32x4*)(src + 4);
  bf16x8 v;
  v[0] = (bf16)u0[0]; v[1] = (bf16)u0[1]; v[2] = (bf16)u0[2]; v[3] = (bf16)u0[3];
  v[4] = (bf16)u1[0]; v[5] = (bf16)u1[1]; v[6] = (bf16)u1[2]; v[7] = (bf16)u1[3];
  return v;
}

__device__ __forceinline__ void store_cvt8(void* dst, const float* __restrict__ src) {
  *(bf16x8*)dst = cvt8(src);
}

// ---------------------------------------------------------------------------
// Main layer, BM=128, 8 waves (512 thr), wave tile 128m x 64n (FLIPPED vs
// R11): wave w owns cols w*64..+63 and ALL 128 rows. Zero B duplication:
// block-wide B traffic per j-step = 32KB (was 64KB w/ 2x dup) -> L2 delivery
// fits inside the 2-wave MFMA window. A-reads double (8 ds_read_b128/wave/j)
// but LDS BW/byte > L2 BW/byte. Swapped MFMA operands: acc = mfma(W, X).
// acc[8 mt][4 nt] = 128 AGPR; B dbuf B0/B1 = 32 VGPR; a[8] = 32 VGPR.
// Epilogue (R8-verified algebra): lane holds m = mt*16+l15, n = col0+nt*16+
// l4*4+r -> one ds_write_b64 per (mt,nt): ksp = w*2+(nt>>1); slot-lane =
// l15 + 16*((nt&1)*2+(l4>>1)); byte = (l4&1)*8; gmt = mt.
// ---------------------------------------------------------------------------
template<int K, bool WSPATH>
__device__ __forceinline__ void run_main_layer(
    const bf16* __restrict__ wb,   // swizzled layout when WSPATH
    const float* __restrict__ wf,  // raw [N][K] fp32 fallback
    const float* __restrict__ bias, char* __restrict__ act,
    int w, int l, int l15, int l4)
{
  constexpr int NKS = K / 32;
  const int col0 = w * 64;
  const char* abase = act + l * 16;

  f32x4 acc[8][4];   // [mt][nt] = 128 AGPR
#pragma unroll
  for (int mt = 0; mt < 8; ++mt)
#pragma unroll
    for (int nt = 0; nt < 4; ++nt)
      acc[mt][nt] = f32x4{0.f, 0.f, 0.f, 0.f};

  if constexpr (WSPATH) {
    const bf16* bp = wb + ((size_t)(w * 4) * NKS * 64 + l) * 8;
    bf16x8 B0[4], B1[4];
#pragma unroll
    for (int i = 0; i < 4; ++i)
      B0[i] = *(const bf16x8*)(bp + (size_t)(i * NKS) * 512);

#pragma unroll
    for (int j = 0; j < NKS; j += 2) {
      if (j + 1 < NKS) {
#pragma unroll
        for (int i = 0; i < 4; ++i)
          B1[i] = *(const bf16x8*)(bp + (size_t)(i * NKS + j + 1) * 512);
      }
      {
        bf16x8 a[8];
#pragma unroll
        for (int mt = 0; mt < 8; ++mt)
          a[mt] = *(const bf16x8*)(abase + (mt * NKS + j) * 1024);
        __builtin_amdgcn_s_setprio(1);
#pragma unroll
        for (int mt = 0; mt < 8; ++mt)
#pragma unroll
          for (int nt = 0; nt < 4; ++nt)
            acc[mt][nt] = __builtin_amdgcn_mfma_f32_16x16x32_bf16(B0[nt], a[mt], acc[mt][nt], 0, 0, 0);
        __builtin_amdgcn_s_setprio(0);
      }
      if (j + 2 < NKS) {
#pragma unroll
        for (int i = 0; i < 4; ++i)
          B0[i] = *(const bf16x8*)(bp + (size_t)(i * NKS + j + 2) * 512);
      }
      if (j + 1 < NKS) {
        bf16x8 a[8];
#pragma unroll
        for (int mt = 0; mt < 8; ++mt)
          a[mt] = *(const bf16x8*)(abase + (mt * NKS + j + 1) * 1024);
        __builtin_amdgcn_s_setprio(1);
#pragma unroll
        for (int mt = 0; mt < 8; ++mt)
#pragma unroll
          for (int nt = 0; nt < 4; ++nt)
            acc[mt][nt] = __builtin_amdgcn_mfma_f32_16x16x32_bf16(B1[nt], a[mt], acc[mt][nt], 0, 0, 0);
        __builtin_amdgcn_s_setprio(0);
      }
    }
  } else {
    const float* bpf[4];
#pragma unroll
    for (int nt = 0; nt < 4; ++nt)
      bpf[nt] = wf + (size_t)(col0 + nt * 16 + l15) * K + l4 * 8;
#pragma unroll
    for (int j = 0; j < NKS; ++j) {
      bf16x8 a[8], b[4];
#pragma unroll
      for (int nt = 0; nt < 4; ++nt) b[nt] = cvt8(bpf[nt] + j * 32);
#pragma unroll
      for (int mt = 0; mt < 8; ++mt)
        a[mt] = *(const bf16x8*)(abase + (mt * NKS + j) * 1024);
#pragma unroll
      for (int mt = 0; mt < 8; ++mt)
#pragma unroll
        for (int nt = 0; nt < 4; ++nt)
          acc[mt][nt] = __builtin_amdgcn_mfma_f32_16x16x32_bf16(b[nt], a[mt], acc[mt][nt], 0, 0, 0);
    }
  }

  __syncthreads();  // all waves done reading act for this layer

  // epilogue: bias+relu, pack 4 consecutive n per thread -> one ds_write_b64
#pragma unroll
  for (int nt = 0; nt < 4; ++nt) {
    const f32x4 bv = *(const f32x4*)(bias + col0 + nt * 16 + l4 * 4);
    const int slot = l15 + ((nt & 1) * 2 + (l4 >> 1)) * 16;
    const int ksp  = w * 2 + (nt >> 1);
    const int boff = slot * 16 + (l4 & 1) * 8;
#pragma unroll
    for (int mt = 0; mt < 8; ++mt) {
      bf16x4 pk;
#pragma unroll
      for (int r = 0; r < 4; ++r) {
        const float v = acc[mt][nt][r] + bv[r];
        pk[r] = (bf16)(v > 0.f ? v : 0.f);
      }
      *(bf16x4*)(act + (mt * 16 + ksp) * 1024 + boff) = pk;
    }
  }
  __syncthreads();  // act ready for next layer
}

// ---------------------------------------------------------------------------
// Final layer, 8 waves: wave w owns mtile w (16 rows), ALL 64 cols (4 frags).
// Register dbuf. Lane: m = w*16+l15, 4 consecutive cols -> global_store_dwordx4.
// ---------------------------------------------------------------------------
template<bool WSPATH>
__device__ __forceinline__ void run_final_layer(
    const bf16* __restrict__ wb, const float* __restrict__ wf,
    const float* __restrict__ bias, const char* __restrict__ act,
    float* __restrict__ gout,
    int w, int l, int l15, int l4)
{
  constexpr int NKS = 16;
  const char* abase = act + w * (NKS * 1024) + l * 16;

  f32x4 acc[4];
#pragma unroll
  for (int f = 0; f < 4; ++f) acc[f] = f32x4{0.f, 0.f, 0.f, 0.f};

  if constexpr (WSPATH) {
    const bf16* bp = wb + (size_t)l * 8;
    bf16x8 B0[4], B1[4];
#pragma unroll
    for (int f = 0; f < 4; ++f)
      B0[f] = *(const bf16x8*)(bp + (size_t)(f * NKS) * 512);
#pragma unroll
    for (int j = 0; j < NKS; j += 2) {
      {
#pragma unroll
        for (int f = 0; f < 4; ++f)
          B1[f] = *(const bf16x8*)(bp + (size_t)(f * NKS + j + 1) * 512);
        const bf16x8 a = *(const bf16x8*)(abase + j * 1024);
#pragma unroll
        for (int f = 0; f < 4; ++f)
          acc[f] = __builtin_amdgcn_mfma_f32_16x16x32_bf16(B0[f], a, acc[f], 0, 0, 0);
      }
      {
        if (j + 2 < NKS) {
#pragma unroll
          for (int f = 0; f < 4; ++f)
            B0[f] = *(const bf16x8*)(bp + (size_t)(f * NKS + j + 2) * 512);
        }
        const bf16x8 a = *(const bf16x8*)(abase + (j + 1) * 1024);
#pragma unroll
        for (int f = 0; f < 4; ++f)
          acc[f] = __builtin_amdgcn_mfma_f32_16x16x32_bf16(B1[f], a, acc[f], 0, 0, 0);
      }
    }
  } else {
    const float* bpf[4];
#pragma unroll
    for (int f = 0; f < 4; ++f)
      bpf[f] = wf + (size_t)(f * 16 + l15) * UN + l4 * 8;
#pragma unroll
    for (int j = 0; j < NKS; ++j) {
      const bf16x8 a = *(const bf16x8*)(abase + j * 1024);
#pragma unroll
      for (int f = 0; f < 4; ++f) {
        const bf16x8 b = cvt8(bpf[f] + j * 32);
        acc[f] = __builtin_amdgcn_mfma_f32_16x16x32_bf16(b, a, acc[f], 0, 0, 0);
      }
    }
  }

#pragma unroll
  for (int f = 0; f < 4; ++f) {
    const f32x4 bv = *(const f32x4*)(bias + f * 16 + l4 * 4);
    f32x4 o;
#pragma unroll
    for (int r = 0; r < 4; ++r) o[r] = acc[f][r] + bv[r];
    *(f32x4*)(gout + (size_t)(w * 16 + l15) * FOUT + f * 16 + l4 * 4) = o;
  }
}

template<bool WSPATH>
__global__ __launch_bounds__(512, 2) void mlp_fused(
    const float* __restrict__ x,
    const float* __restrict__ w0f, const float* __restrict__ w1f,
    const float* __restrict__ w2f, const float* __restrict__ w3f,
    const float* __restrict__ b0, const float* __restrict__ b1,
    const float* __restrict__ b2, const float* __restrict__ b3,
    const bf16* __restrict__ wbase,
    float* __restrict__ out)
{
  extern __shared__ char smem[];
  char* act = smem;  // 128 KiB activations, frag order (only LDS use)

  const int tid = threadIdx.x;
  const int w = tid >> 6, l = tid & 63;
  const int l15 = l & 15, l4 = l >> 4;

  // XCD-chunked swizzle (2048 % 8 == 0 -> bijective): each XCD owns one channel
  const int wg = (blockIdx.x & 7) * 256 + (blockIdx.x >> 3);
  const int ch = wg >> 8;
  const int row0 = (wg & 255) * BM;

  const bf16* w0b = wbase + (size_t)ch * UN * FIN;
  const bf16* w1b = wbase + CH * UN * FIN + (size_t)ch * UN * UN;
  const bf16* w2b = wbase + CH * UN * FIN + CH * UN * UN + (size_t)ch * UN * UN;
  const bf16* w3b = wbase + CH * UN * FIN + 2 * CH * UN * UN + (size_t)ch * FOUT * UN;
  const float* w0c = w0f + (size_t)ch * UN * FIN;
  const float* w1c = w1f + (size_t)ch * UN * UN;
  const float* w2c = w2f + (size_t)ch * UN * UN;
  const float* w3c = w3f + (size_t)ch * FOUT * UN;
  const float* b0c = b0 + ch * UN;
  const float* b1c = b1 + ch * UN;
  const float* b2c = b2 + ch * UN;
  const float* b3c = b3 + ch * FOUT;

  // stage x tile (128 x 64 fp32 -> bf16): 16 slots, 8 waves -> 2 slots/wave
  {
    const float* xs = x + (size_t)(ch * SEC + row0) * FIN;
#pragma unroll
    for (int i = 0; i < 2; ++i) {
      const int s = w * 2 + i;   // slot = gmt*2 + ks
      store_cvt8(act + s * 1024 + l * 16,
                 xs + ((s >> 1) * 16 + l15) * FIN + (s & 1) * 32 + l4 * 8);
    }
  }
  __syncthreads();

  run_main_layer<64,  WSPATH>(w0b, w0c, b0c, act, w, l, l15, l4);
  run_main_layer<512, WSPATH>(w1b, w1c, b1c, act, w, l, l15, l4);
  run_main_layer<512, WSPATH>(w2b, w2c, b2c, act, w, l, l15, l4);
  run_final_layer<WSPATH>(w3b, w3c, b3c, act,
                          out + (size_t)(ch * SEC + row0) * FOUT,
                          w, l, l15, l4);
}

// ---------------------------------------------------------------------------
// fp32 -> bf16 weight conversion into d_ws, SWIZZLED to MFMA-fragment order:
// per channel, element (f, ks, l, j) = W[f*16 + (l&15)][ks*32 + (l>>4)*8 + j]
// stored at ((f*NKS + ks)*64 + l)*8 + j.
// ---------------------------------------------------------------------------
template<int K, int N>
__device__ __forceinline__ void cvt_one(const float* __restrict__ src,
                                        bf16* __restrict__ dst, int t)
{
  constexpr int NKS = K / 32;
  constexpr int perCh = N * K / 8;   // triples per channel (pow2)
  const int ch = t / perCh;
  const int r = t - ch * perCh;
  const int l = r & 63;
  const int p = r >> 6;
  const int ks = p & (NKS - 1);
  const int f = p / NKS;
  const float* s = src + (size_t)ch * N * K + (size_t)(f * 16 + (l & 15)) * K
                 + ks * 32 + (l >> 4) * 8;
  store_cvt8(dst + (size_t)t * 8, s);
}

__global__ void cvt_weights(const float* __restrict__ w0, const float* __restrict__ w1,
                            const float* __restrict__ w2, const float* __restrict__ w3,
                            bf16* __restrict__ o)
{
  constexpr int T0 = CH * UN * FIN / 8;   // 32768 triples
  constexpr int T1 = CH * UN * UN / 8;    // 262144
  constexpr int total = 2 * T0 + 2 * T1;  // 589824
  for (int t = blockIdx.x * blockDim.x + threadIdx.x; t < total;
       t += gridDim.x * blockDim.x) {
    if (t < T0)                cvt_one<FIN, UN>(w0, o, t);
    else if (t < T0 + T1)      cvt_one<UN, UN>(w1, o + CH * UN * FIN, t - T0);
    else if (t < T0 + 2 * T1)  cvt_one<UN, UN>(w2, o + CH * UN * FIN + CH * UN * UN, t - T0 - T1);
    else                       cvt_one<UN, FOUT>(w3, o + CH * UN * FIN + 2 * CH * UN * UN, t - T0 - 2 * T1);
  }
}

extern "C" void kernel_launch(void* const* d_in, const int* in_sizes, int n_in,
                              void* d_out, int out_size, void* d_ws, size_t ws_size,
                              hipStream_t stream)
{
  const float* x  = (const float*)d_in[0];
  const float* w0 = (const float*)d_in[1];
  const float* w1 = (const float*)d_in[2];
  const float* w2 = (const float*)d_in[3];
  const float* w3 = (const float*)d_in[4];
  const float* b0 = (const float*)d_in[5];
  const float* b1 = (const float*)d_in[6];
  const float* b2 = (const float*)d_in[7];
  const float* b3 = (const float*)d_in[8];
  float* out = (float*)d_out;

  const int grid = CH * (SEC / BM);            // 2048 blocks
  const size_t wbytes = (size_t)(2 * CH * UN * FIN + 2 * CH * UN * UN) * 2;  // 9437184

  if (ws_size >= wbytes) {
    bf16* wb = (bf16*)d_ws;
    hipLaunchKernelGGL(cvt_weights, dim3(2304), dim3(256), 0, stream, w0, w1, w2, w3, wb);
    hipFuncSetAttribute(reinterpret_cast<const void*>(mlp_fused<true>),
                        hipFuncAttributeMaxDynamicSharedMemorySize, 131072);
    hipLaunchKernelGGL(mlp_fused<true>, dim3(grid), dim3(512), 131072, stream,
                       x, w0, w1, w2, w3, b0, b1, b2, b3, wb, out);
  } else {
    hipFuncSetAttribute(reinterpret_cast<const void*>(mlp_fused<false>),
                        hipFuncAttributeMaxDynamicSharedMemorySize, 131072);
    hipLaunchKernelGGL(mlp_fused<false>, dim3(grid), dim3(512), 131072, stream,
                       x, w0, w1, w2, w3, b0, b1, b2, b3, (const bf16*)nullptr, out);
  }
}

// Round 13
// 293.347 us; speedup vs baseline: 1.4607x; 1.0056x over previous
//
#include <hip/hip_runtime.h>
#include <hip/hip_bf16.h>

#define CH 8
#define SEC 32768
#define FIN 64
#define FOUT 64
#define UN 512
#define BM 128

typedef __bf16 bf16;
typedef bf16 bf16x8 __attribute__((ext_vector_type(8)));
typedef bf16 bf16x4 __attribute__((ext_vector_type(4)));
typedef float f32x4 __attribute__((ext_vector_type(4)));
typedef float f32x16 __attribute__((ext_vector_type(16)));

// load 8 consecutive fp32 and convert to bf16x8
__device__ __forceinline__ bf16x8 cvt8(const float* __restrict__ src) {
  f32x4 u0 = *(const f32x4*)src;
  f32x4 u1 = *(const f32x4*)(src + 4);
  bf16x8 v;
  v[0] = (bf16)u0[0]; v[1] = (bf16)u0[1]; v[2] = (bf16)u0[2]; v[3] = (bf16)u0[3];
  v[4] = (bf16)u1[0]; v[5] = (bf16)u1[1]; v[6] = (bf16)u1[2]; v[7] = (bf16)u1[3];
  return v;
}

__device__ __forceinline__ void store_cvt8(void* dst, const float* __restrict__ src) {
  *(bf16x8*)dst = cvt8(src);
}

// ---------------------------------------------------------------------------
// 32x32x16 MFMA scheme. Fragments (bf16x8 = 16B/lane):
//   X-frag (B-operand): batch-row m = lane&31, k = (lane>>5)*8 + e
//   W-frag (A-operand): feature   n = lane&31, k = (lane>>5)*8 + e
//   D (acc, f32x16):    col = m = lane&31, row = n = (reg&3)+8*(reg>>2)+4*(lane>>5)
// act LDS layout: [4 mt of 32 rows][NKS = K/16][64 lanes][16B]; K=512 -> 128KiB.
//
// Main layer: BM=128, 8 waves, wave tile 128m x 64n (zero B duplication):
// wave w owns features col0 = w*64 (2 frags of 32), all 4 row-groups.
// acc[4 mt][2 nt] f32x16 = 128 AGPR; A dbuf 32 VGPR + B dbuf 16 VGPR.
// Epilogue: reg-quad q holds 4 CONSECUTIVE features n = col0 + nt*32 + 8q +
// 4hi + r -> one ds_write_b64 per (mt,nt,q):
//   ks' = (col0 + nt*32)/16 + (q>>1); lane' = (q&1)*32 + (l&31); byte = hi*8.
// ---------------------------------------------------------------------------
template<int K, bool WSPATH>
__device__ __forceinline__ void run_main_layer(
    const bf16* __restrict__ wb,   // swizzled layout when WSPATH
    const float* __restrict__ wf,  // raw [N][K] fp32 fallback
    const float* __restrict__ bias, char* __restrict__ act,
    int w, int l, int l31, int hi)
{
  constexpr int NKS = K / 16;
  const int col0 = w * 64;
  const char* abase = act + l * 16;

  f32x16 acc[4][2];
#pragma unroll
  for (int mt = 0; mt < 4; ++mt)
#pragma unroll
    for (int nt = 0; nt < 2; ++nt)
#pragma unroll
      for (int r = 0; r < 16; ++r) acc[mt][nt][r] = 0.f;

  if constexpr (WSPATH) {
    const bf16* bp = wb + ((size_t)(w * 2) * NKS * 64 + l) * 8;
    bf16x8 B0[2], B1[2], A0[4], A1[4];
#pragma unroll
    for (int i = 0; i < 2; ++i)
      B0[i] = *(const bf16x8*)(bp + (size_t)(i * NKS) * 512);
#pragma unroll
    for (int mt = 0; mt < 4; ++mt)
      A0[mt] = *(const bf16x8*)(abase + (mt * NKS) * 1024);

#pragma unroll
    for (int j = 0; j < NKS; j += 2) {
      {
        if (j + 1 < NKS) {
#pragma unroll
          for (int i = 0; i < 2; ++i)
            B1[i] = *(const bf16x8*)(bp + (size_t)(i * NKS + j + 1) * 512);
#pragma unroll
          for (int mt = 0; mt < 4; ++mt)
            A1[mt] = *(const bf16x8*)(abase + (mt * NKS + j + 1) * 1024);
        }
        __builtin_amdgcn_s_setprio(1);
#pragma unroll
        for (int mt = 0; mt < 4; ++mt)
#pragma unroll
          for (int nt = 0; nt < 2; ++nt)
            acc[mt][nt] = __builtin_amdgcn_mfma_f32_32x32x16_bf16(B0[nt], A0[mt], acc[mt][nt], 0, 0, 0);
        __builtin_amdgcn_s_setprio(0);
      }
      if (j + 1 < NKS) {
        if (j + 2 < NKS) {
#pragma unroll
          for (int i = 0; i < 2; ++i)
            B0[i] = *(const bf16x8*)(bp + (size_t)(i * NKS + j + 2) * 512);
#pragma unroll
          for (int mt = 0; mt < 4; ++mt)
            A0[mt] = *(const bf16x8*)(abase + (mt * NKS + j + 2) * 1024);
        }
        __builtin_amdgcn_s_setprio(1);
#pragma unroll
        for (int mt = 0; mt < 4; ++mt)
#pragma unroll
          for (int nt = 0; nt < 2; ++nt)
            acc[mt][nt] = __builtin_amdgcn_mfma_f32_32x32x16_bf16(B1[nt], A1[mt], acc[mt][nt], 0, 0, 0);
        __builtin_amdgcn_s_setprio(0);
      }
    }
  } else {
    // fallback: raw [N][K] fp32, n = col0 + nt*32 + (l&31), k = j*16 + hi*8
    const float* bpf[2];
#pragma unroll
    for (int nt = 0; nt < 2; ++nt)
      bpf[nt] = wf + (size_t)(col0 + nt * 32 + l31) * K + hi * 8;
#pragma unroll
    for (int j = 0; j < NKS; ++j) {
      bf16x8 a[4], b[2];
#pragma unroll
      for (int nt = 0; nt < 2; ++nt) b[nt] = cvt8(bpf[nt] + j * 16);
#pragma unroll
      for (int mt = 0; mt < 4; ++mt)
        a[mt] = *(const bf16x8*)(abase + (mt * NKS + j) * 1024);
#pragma unroll
      for (int mt = 0; mt < 4; ++mt)
#pragma unroll
        for (int nt = 0; nt < 2; ++nt)
          acc[mt][nt] = __builtin_amdgcn_mfma_f32_32x32x16_bf16(b[nt], a[mt], acc[mt][nt], 0, 0, 0);
    }
  }

  __syncthreads();  // all waves done reading act for this layer

  // epilogue: bias+relu, one ds_write_b64 per (mt, nt, quad); next NKS' = 32
#pragma unroll
  for (int nt = 0; nt < 2; ++nt) {
#pragma unroll
    for (int q = 0; q < 4; ++q) {
      const f32x4 bv = *(const f32x4*)(bias + col0 + nt * 32 + q * 8 + hi * 4);
      const int ksp  = (col0 >> 4) + nt * 2 + (q >> 1);
      const int boff = ((q & 1) * 32 + l31) * 16 + hi * 8;
#pragma unroll
      for (int mt = 0; mt < 4; ++mt) {
        bf16x4 pk;
#pragma unroll
        for (int r = 0; r < 4; ++r) {
          const float v = acc[mt][nt][q * 4 + r] + bv[r];
          pk[r] = (bf16)(v > 0.f ? v : 0.f);
        }
        *(bf16x4*)(act + (mt * 32 + ksp) * 1024 + boff) = pk;
      }
    }
  }
  __syncthreads();  // act ready for next layer
}

// ---------------------------------------------------------------------------
// Final layer: 128x64 output = 4m x 2n tiles of 32x32; wave w -> tm = w>>1,
// tn = w&1, one acc f32x16. Lane: m = tm*32 + (l&31); quad q -> 4 consecutive
// cols n = tn*32 + 8q + 4hi + r -> global_store_dwordx4. No relu.
// ---------------------------------------------------------------------------
template<bool WSPATH>
__device__ __forceinline__ void run_final_layer(
    const bf16* __restrict__ wb, const float* __restrict__ wf,
    const float* __restrict__ bias, const char* __restrict__ act,
    float* __restrict__ gout,
    int w, int l, int l31, int hi)
{
  constexpr int NKS = 32;
  const int tm = w >> 1, tn = w & 1;
  const char* abase = act + tm * (NKS * 1024) + l * 16;

  f32x16 acc;
#pragma unroll
  for (int r = 0; r < 16; ++r) acc[r] = 0.f;

  if constexpr (WSPATH) {
    const bf16* bp = wb + ((size_t)tn * NKS * 64 + l) * 8;
    bf16x8 B0 = *(const bf16x8*)(bp), B1;
    bf16x8 A0 = *(const bf16x8*)(abase), A1;
#pragma unroll
    for (int j = 0; j < NKS; j += 2) {
      {
        B1 = *(const bf16x8*)(bp + (size_t)(j + 1) * 512);
        A1 = *(const bf16x8*)(abase + (j + 1) * 1024);
        acc = __builtin_amdgcn_mfma_f32_32x32x16_bf16(B0, A0, acc, 0, 0, 0);
      }
      {
        if (j + 2 < NKS) {
          B0 = *(const bf16x8*)(bp + (size_t)(j + 2) * 512);
          A0 = *(const bf16x8*)(abase + (j + 2) * 1024);
        }
        acc = __builtin_amdgcn_mfma_f32_32x32x16_bf16(B1, A1, acc, 0, 0, 0);
      }
    }
  } else {
    const float* bpf = wf + (size_t)(tn * 32 + l31) * UN + hi * 8;
#pragma unroll
    for (int j = 0; j < NKS; ++j) {
      const bf16x8 b = cvt8(bpf + j * 16);
      const bf16x8 a = *(const bf16x8*)(abase + j * 1024);
      acc = __builtin_amdgcn_mfma_f32_32x32x16_bf16(b, a, acc, 0, 0, 0);
    }
  }

#pragma unroll
  for (int q = 0; q < 4; ++q) {
    const f32x4 bv = *(const f32x4*)(bias + tn * 32 + q * 8 + hi * 4);
    f32x4 o;
#pragma unroll
    for (int r = 0; r < 4; ++r) o[r] = acc[q * 4 + r] + bv[r];
    *(f32x4*)(gout + (size_t)(tm * 32 + l31) * FOUT + tn * 32 + q * 8 + hi * 4) = o;
  }
}

template<bool WSPATH>
__global__ __launch_bounds__(512, 2) void mlp_fused(
    const float* __restrict__ x,
    const float* __restrict__ w0f, const float* __restrict__ w1f,
    const float* __restrict__ w2f, const float* __restrict__ w3f,
    const float* __restrict__ b0, const float* __restrict__ b1,
    const float* __restrict__ b2, const float* __restrict__ b3,
    const bf16* __restrict__ wbase,
    float* __restrict__ out)
{
  extern __shared__ char smem[];
  char* act = smem;  // 128 KiB activations, 32x32-frag order

  const int tid = threadIdx.x;
  const int w = tid >> 6, l = tid & 63;
  const int l31 = l & 31, hi = l >> 5;

  // XCD-chunked swizzle (2048 % 8 == 0 -> bijective): each XCD owns one channel
  const int wg = (blockIdx.x & 7) * 256 + (blockIdx.x >> 3);
  const int ch = wg >> 8;
  const int row0 = (wg & 255) * BM;

  const bf16* w0b = wbase + (size_t)ch * UN * FIN;
  const bf16* w1b = wbase + CH * UN * FIN + (size_t)ch * UN * UN;
  const bf16* w2b = wbase + CH * UN * FIN + CH * UN * UN + (size_t)ch * UN * UN;
  const bf16* w3b = wbase + CH * UN * FIN + 2 * CH * UN * UN + (size_t)ch * FOUT * UN;
  const float* w0c = w0f + (size_t)ch * UN * FIN;
  const float* w1c = w1f + (size_t)ch * UN * UN;
  const float* w2c = w2f + (size_t)ch * UN * UN;
  const float* w3c = w3f + (size_t)ch * FOUT * UN;
  const float* b0c = b0 + ch * UN;
  const float* b1c = b1 + ch * UN;
  const float* b2c = b2 + ch * UN;
  const float* b3c = b3 + ch * FOUT;

  // stage x tile (128 x 64) into act: slots s = mt*4 + ks (NKS=4), 2 per wave
  {
    const float* xs = x + (size_t)(ch * SEC + row0) * FIN;
#pragma unroll
    for (int i = 0; i < 2; ++i) {
      const int s = w * 2 + i;
      const int mt = s >> 2, ks = s & 3;
      store_cvt8(act + s * 1024 + l * 16,
                 xs + (size_t)(mt * 32 + l31) * FIN + ks * 16 + hi * 8);
    }
  }
  __syncthreads();

  run_main_layer<64,  WSPATH>(w0b, w0c, b0c, act, w, l, l31, hi);
  run_main_layer<512, WSPATH>(w1b, w1c, b1c, act, w, l, l31, hi);
  run_main_layer<512, WSPATH>(w2b, w2c, b2c, act, w, l, l31, hi);
  run_final_layer<WSPATH>(w3b, w3c, b3c, act,
                          out + (size_t)(ch * SEC + row0) * FOUT,
                          w, l, l31, hi);
}

// ---------------------------------------------------------------------------
// fp32 -> bf16 weight conversion into d_ws, swizzled to 32x32 W-frag order:
// per channel, element (f, ks, l, e) = W[f*32 + (l&31)][ks*16 + (l>>5)*8 + e]
// stored at ((f*NKS + ks)*64 + l)*8 + e, NKS = K/16.
// ---------------------------------------------------------------------------
template<int K, int N>
__device__ __forceinline__ void cvt_one(const float* __restrict__ src,
                                        bf16* __restrict__ dst, int t)
{
  constexpr int NKS = K / 16;
  constexpr int perCh = N * K / 8;   // 8-elem groups per channel (pow2)
  const int ch = t / perCh;
  const int r = t - ch * perCh;
  const int l = r & 63;
  const int p = r >> 6;
  const int ks = p & (NKS - 1);
  const int f = p / NKS;
  const float* s = src + (size_t)ch * N * K + (size_t)(f * 32 + (l & 31)) * K
                 + ks * 16 + (l >> 5) * 8;
  store_cvt8(dst + (size_t)t * 8, s);
}

__global__ void cvt_weights(const float* __restrict__ w0, const float* __restrict__ w1,
                            const float* __restrict__ w2, const float* __restrict__ w3,
                            bf16* __restrict__ o)
{
  constexpr int T0 = CH * UN * FIN / 8;   // 32768
  constexpr int T1 = CH * UN * UN / 8;    // 262144
  constexpr int total = 2 * T0 + 2 * T1;  // 589824
  for (int t = blockIdx.x * blockDim.x + threadIdx.x; t < total;
       t += gridDim.x * blockDim.x) {
    if (t < T0)                cvt_one<FIN, UN>(w0, o, t);
    else if (t < T0 + T1)      cvt_one<UN, UN>(w1, o + CH * UN * FIN, t - T0);
    else if (t < T0 + 2 * T1)  cvt_one<UN, UN>(w2, o + CH * UN * FIN + CH * UN * UN, t - T0 - T1);
    else                       cvt_one<UN, FOUT>(w3, o + CH * UN * FIN + 2 * CH * UN * UN, t - T0 - 2 * T1);
  }
}

extern "C" void kernel_launch(void* const* d_in, const int* in_sizes, int n_in,
                              void* d_out, int out_size, void* d_ws, size_t ws_size,
                              hipStream_t stream)
{
  const float* x  = (const float*)d_in[0];
  const float* w0 = (const float*)d_in[1];
  const float* w1 = (const float*)d_in[2];
  const float* w2 = (const float*)d_in[3];
  const float* w3 = (const float*)d_in[4];
  const float* b0 = (const float*)d_in[5];
  const float* b1 = (const float*)d_in[6];
  const float* b2 = (const float*)d_in[7];
  const float* b3 = (const float*)d_in[8];
  float* out = (float*)d_out;

  const int grid = CH * (SEC / BM);            // 2048 blocks
  const size_t wbytes = (size_t)(2 * CH * UN * FIN + 2 * CH * UN * UN) * 2;  // 9437184

  if (ws_size >= wbytes) {
    bf16* wb = (bf16*)d_ws;
    hipLaunchKernelGGL(cvt_weights, dim3(2304), dim3(256), 0, stream, w0, w1, w2, w3, wb);
    hipFuncSetAttribute(reinterpret_cast<const void*>(mlp_fused<true>),
                        hipFuncAttributeMaxDynamicSharedMemorySize, 131072);
    hipLaunchKernelGGL(mlp_fused<true>, dim3(grid), dim3(512), 131072, stream,
                       x, w0, w1, w2, w3, b0, b1, b2, b3, wb, out);
  } else {
    hipFuncSetAttribute(reinterpret_cast<const void*>(mlp_fused<false>),
                        hipFuncAttributeMaxDynamicSharedMemorySize, 131072);
    hipLaunchKernelGGL(mlp_fused<false>, dim3(grid), dim3(512), 131072, stream,
                       x, w0, w1, w2, w3, b0, b1, b2, b3, (const bf16*)nullptr, out);
  }
}